// Round 1
// baseline (246.780 us; speedup 1.0000x reference)
//
#include <hip/hip_runtime.h>
#include <hip/hip_bf16.h>

// Problem constants
constexpr int NB = 8;      // batch
constexpr int T  = 2048;   // seq
constexpr int C  = 1024;   // embed
constexpr int Hd = 128;    // head size

typedef short bf16x8 __attribute__((ext_vector_type(8)));
typedef float floatx4 __attribute__((ext_vector_type(4)));

__device__ inline short f2bf(float x) {
    return __builtin_bit_cast(short, __float2bfloat16(x));
}

// ---------------------------------------------------------------------------
// Kernel 1: QKV projection. C_out[m][n] = sum_c X[m][c] * W[n][c]  (x @ W.T)
// One GEMM, M=16384, K=1024; blockIdx.y selects which W / destination.
// Q gets scale = log2(e)/sqrt(128) folded in so attention can use exp2.
// ---------------------------------------------------------------------------
__global__ __launch_bounds__(256) void qkv_proj(
    const float* __restrict__ X,
    const float* __restrict__ Wq, const float* __restrict__ Wk,
    const float* __restrict__ Wv,
    ushort* __restrict__ Q, ushort* __restrict__ Ko, ushort* __restrict__ Vo)
{
    __shared__ short Al[128][40];   // 128 rows x 32 cols bf16, +8 pad (2-way banks, free)
    __shared__ short Bl[128][40];

    const int bm = blockIdx.x;               // 0..127  (M tiles of 128)
    const int bn = blockIdx.y;               // 0..2    (Q/K/V)
    const float* W = (bn == 0) ? Wq : (bn == 1) ? Wk : Wv;
    ushort* dst    = (bn == 0) ? Q  : (bn == 1) ? Ko : Vo;
    // log2(e) / sqrt(128) folded into Q only
    const float scale = (bn == 0) ? 0.12751744f : 1.0f;

    const int m0   = bm * 128;
    const int tid  = threadIdx.x;
    const int lane = tid & 63;
    const int wave = tid >> 6;               // 0..3
    const int quad = lane >> 4;
    const int colL = lane & 15;
    const int wm = (wave & 1) * 64;
    const int wn = (wave >> 1) * 64;

    floatx4 acc[4][4] = {};

    for (int c0 = 0; c0 < C; c0 += 32) {
        // stage A (X tile 128x32 fp32 -> bf16) and B (W tile 128x32)
        for (int t = 0; t < 4; ++t) {
            int idx = tid + t * 256;          // 0..1023
            int r  = idx >> 3;                // 0..127
            int c4 = idx & 7;                 // 8 chunks of 4 floats
            float4 va = *(const float4*)&X[(size_t)(m0 + r) * C + c0 + c4 * 4];
            short4 sa;
            sa.x = f2bf(va.x); sa.y = f2bf(va.y); sa.z = f2bf(va.z); sa.w = f2bf(va.w);
            *(short4*)&Al[r][c4 * 4] = sa;
            float4 vb = *(const float4*)&W[(size_t)r * C + c0 + c4 * 4];
            short4 sb;
            sb.x = f2bf(vb.x); sb.y = f2bf(vb.y); sb.z = f2bf(vb.z); sb.w = f2bf(vb.w);
            *(short4*)&Bl[r][c4 * 4] = sb;
        }
        __syncthreads();

        bf16x8 a[4], b[4];
        for (int mt = 0; mt < 4; ++mt)
            a[mt] = *(const bf16x8*)&Al[wm + mt * 16 + colL][quad * 8];
        for (int nt = 0; nt < 4; ++nt)
            b[nt] = *(const bf16x8*)&Bl[wn + nt * 16 + colL][quad * 8];
        for (int mt = 0; mt < 4; ++mt)
            for (int nt = 0; nt < 4; ++nt)
                acc[mt][nt] = __builtin_amdgcn_mfma_f32_16x16x32_bf16(
                    a[mt], b[nt], acc[mt][nt], 0, 0, 0);
        __syncthreads();
    }

    // epilogue: C/D layout col=lane&15, row=quad*4+reg
    for (int mt = 0; mt < 4; ++mt)
        for (int nt = 0; nt < 4; ++nt)
            for (int r = 0; r < 4; ++r) {
                int row = m0 + wm + mt * 16 + quad * 4 + r;   // 0..16383
                int col = wn + nt * 16 + colL;                // 0..127
                dst[(size_t)row * Hd + col] =
                    (ushort)f2bf(acc[mt][nt][r] * scale);
            }
}

// ---------------------------------------------------------------------------
// Kernel 2: V [b][t][h] -> Vt [b][h][t]  (bf16), 64x64 tiles through LDS
// ---------------------------------------------------------------------------
__global__ __launch_bounds__(256) void transpose_v(
    const ushort* __restrict__ V, ushort* __restrict__ Vt)
{
    __shared__ ushort tl[64][68];
    const int t0 = blockIdx.x * 64;
    const int h0 = blockIdx.y * 64;
    const int b  = blockIdx.z;
    const int tid = threadIdx.x;

    for (int it = 0; it < 4; ++it) {
        int idx = tid + it * 256;             // 0..1023
        int r  = idx >> 4;                    // t row 0..63
        int c4 = idx & 15;                    // 16 chunks of 4
        ushort4 v = *(const ushort4*)&V[(size_t)(b * T + t0 + r) * Hd + h0 + c4 * 4];
        *(ushort4*)&tl[r][c4 * 4] = v;
    }
    __syncthreads();
    for (int it = 0; it < 4; ++it) {
        int idx = tid + it * 256;
        int rh = idx >> 4;                    // h row 0..63
        int c4 = idx & 15;                    // t chunks of 4
        ushort4 o;
        o.x = tl[c4 * 4 + 0][rh];
        o.y = tl[c4 * 4 + 1][rh];
        o.z = tl[c4 * 4 + 2][rh];
        o.w = tl[c4 * 4 + 3][rh];
        *(ushort4*)&Vt[(size_t)(b * Hd + h0 + rh) * T + t0 + c4 * 4] = o;
    }
}

// ---------------------------------------------------------------------------
// Kernel 3: causal flash attention.
// BM=32 q-rows per block (wave w owns rows [q0+16w, q0+16w+16)), BN=64 keys.
// Q pre-scaled by log2e/sqrt(H) -> use exp2. 512 blocks, heavy/light swizzle.
// ---------------------------------------------------------------------------
__global__ __launch_bounds__(128) void attn(
    const ushort* __restrict__ Q, const ushort* __restrict__ Kg,
    const ushort* __restrict__ Vt, float* __restrict__ out)
{
    __shared__ short Kl[64][136];   // [key][h], +8 pad
    __shared__ short Vl[128][72];   // [h][key] (from Vt), +8 pad
    __shared__ short Pl[2][16][72]; // per-wave P scratch, +8 pad

    const int g = blockIdx.x;
    const int jlin = g >> 3;                      // 0..63
    const int b    = g & 7;
    // pair heavy and light q-tiles on the same CU: 0,2,..,62,63,61,..,1
    const int j  = (jlin < 32) ? (2 * jlin) : (63 - 2 * (jlin - 32));
    const int q0 = j * 32;

    const int tid  = threadIdx.x;
    const int lane = tid & 63;
    const int wave = tid >> 6;                    // 0..1
    const int quad = lane >> 4;
    const int colL = lane & 15;

    // Q fragments (A-operand: m=lane&15, k=quad*8+j), kept in regs all iters
    bf16x8 qa[4];
    {
        const int qrow = q0 + wave * 16 + colL;
        const ushort* qp = &Q[(size_t)(b * T + qrow) * Hd];
        for (int ks = 0; ks < 4; ++ks)
            qa[ks] = *(const bf16x8*)&qp[ks * 32 + quad * 8];
    }

    float m_r[4], l_r[4];
    for (int r = 0; r < 4; ++r) { m_r[r] = -__builtin_inff(); l_r[r] = 0.f; }
    floatx4 Oacc[8] = {};

    const int ntiles = (q0 + 31) / 64 + 1;
    for (int it = 0; it < ntiles; ++it) {
        const int k0 = it * 64;
        // stage K tile [64][128]
        for (int t = 0; t < 8; ++t) {
            int idx = tid + t * 128;              // 0..1023
            int r  = idx >> 4;                    // 0..63
            int c8 = idx & 15;                    // 16 chunks of 8 bf16
            float4 v = *(const float4*)&Kg[(size_t)(b * T + k0 + r) * Hd + c8 * 8];
            *(float4*)&Kl[r][c8 * 8] = v;
        }
        // stage Vt tile [128][64]
        for (int t = 0; t < 8; ++t) {
            int idx = tid + t * 128;
            int r  = idx >> 3;                    // h 0..127
            int c8 = idx & 7;                     // 8 chunks of 8 bf16
            float4 v = *(const float4*)&Vt[(size_t)(b * Hd + r) * T + k0 + c8 * 8];
            *(float4*)&Vl[r][c8 * 8] = v;
        }
        __syncthreads();

        // S = Q K^T : 4 C-tiles (16 q x 64 keys), k-dim = 128 = 4 steps
        floatx4 accS[4] = {};
        for (int ks = 0; ks < 4; ++ks)
            for (int nt = 0; nt < 4; ++nt) {
                bf16x8 kb = *(const bf16x8*)&Kl[nt * 16 + colL][ks * 32 + quad * 8];
                accS[nt] = __builtin_amdgcn_mfma_f32_16x16x32_bf16(
                    qa[ks], kb, accS[nt], 0, 0, 0);
            }

        // causal mask (only ever needed on the last tile)
        if (it == ntiles - 1) {
            for (int nt = 0; nt < 4; ++nt)
                for (int r = 0; r < 4; ++r) {
                    int colg = k0 + nt * 16 + colL;
                    int rowg = q0 + wave * 16 + quad * 4 + r;
                    if (colg > rowg) accS[nt][r] = -__builtin_inff();
                }
        }

        // online softmax (rows live across the 16 lanes of a quad)
        float mnew[4], alpha[4], rsum[4];
        for (int r = 0; r < 4; ++r) {
            float mx = fmaxf(fmaxf(accS[0][r], accS[1][r]),
                             fmaxf(accS[2][r], accS[3][r]));
            for (int off = 1; off < 16; off <<= 1)
                mx = fmaxf(mx, __shfl_xor(mx, off, 64));
            mnew[r]  = fmaxf(m_r[r], mx);
            alpha[r] = __builtin_amdgcn_exp2f(m_r[r] - mnew[r]);
            rsum[r]  = 0.f;
        }
        for (int nt = 0; nt < 4; ++nt)
            for (int r = 0; r < 4; ++r) {
                float p = __builtin_amdgcn_exp2f(accS[nt][r] - mnew[r]);
                rsum[r] += p;
                Pl[wave][quad * 4 + r][nt * 16 + colL] = f2bf(p);
            }
        for (int r = 0; r < 4; ++r) {
            float s = rsum[r];
            for (int off = 1; off < 16; off <<= 1)
                s += __shfl_xor(s, off, 64);
            l_r[r] = l_r[r] * alpha[r] + s;
            m_r[r] = mnew[r];
        }
        for (int th = 0; th < 8; ++th)
            for (int r = 0; r < 4; ++r) Oacc[th][r] *= alpha[r];

        // P (C-layout) -> A-layout via per-wave LDS round-trip, then O += P V
        bf16x8 pa[2];
        for (int ks2 = 0; ks2 < 2; ++ks2)
            pa[ks2] = *(const bf16x8*)&Pl[wave][colL][ks2 * 32 + quad * 8];
        for (int th = 0; th < 8; ++th)
            for (int ks2 = 0; ks2 < 2; ++ks2) {
                bf16x8 vb = *(const bf16x8*)&Vl[th * 16 + colL][ks2 * 32 + quad * 8];
                Oacc[th] = __builtin_amdgcn_mfma_f32_16x16x32_bf16(
                    pa[ks2], vb, Oacc[th], 0, 0, 0);
            }
        __syncthreads();
    }

    // epilogue: divide by l, write fp32 out [b][t][h]
    for (int r = 0; r < 4; ++r) {
        float inv = 1.0f / l_r[r];
        int row = q0 + wave * 16 + quad * 4 + r;
        for (int th = 0; th < 8; ++th) {
            int col = th * 16 + colL;
            out[(size_t)(b * T + row) * Hd + col] = Oacc[th][r] * inv;
        }
    }
}

// ---------------------------------------------------------------------------
extern "C" void kernel_launch(void* const* d_in, const int* in_sizes, int n_in,
                              void* d_out, int out_size, void* d_ws, size_t ws_size,
                              hipStream_t stream) {
    const float* x  = (const float*)d_in[0];   // [8,2048,1024]
    const float* Wq = (const float*)d_in[1];   // [128,1024]
    const float* Wk = (const float*)d_in[2];
    const float* Wv = (const float*)d_in[3];
    float* out = (float*)d_out;                // [8,2048,128] fp32

    // workspace: Q,K,V,Vt bf16, 4MB each = 16MB total
    const size_t elems = (size_t)NB * T * Hd;  // 2,097,152
    ushort* Q  = (ushort*)d_ws;
    ushort* K  = Q + elems;
    ushort* V  = K + elems;
    ushort* Vt = V + elems;

    qkv_proj<<<dim3(128, 3), 256, 0, stream>>>(x, Wq, Wk, Wv, Q, K, V);
    transpose_v<<<dim3(T / 64, Hd / 64, NB), 256, 0, stream>>>(V, Vt);
    attn<<<512, 128, 0, stream>>>(Q, K, Vt, out);
}

// Round 2
// 209.224 us; speedup vs baseline: 1.1795x; 1.1795x over previous
//
#include <hip/hip_runtime.h>
#include <hip/hip_bf16.h>

constexpr int NB = 8;      // batch
constexpr int T  = 2048;   // seq
constexpr int C  = 1024;   // embed
constexpr int Hd = 128;    // head size

typedef short bf16x8 __attribute__((ext_vector_type(8)));
typedef float floatx4 __attribute__((ext_vector_type(4)));

__device__ __forceinline__ ushort f2bf(float x) {
    return __builtin_bit_cast(ushort, __float2bfloat16(x));
}
__device__ __forceinline__ float bf2f(ushort u) {
    unsigned int x = ((unsigned int)u) << 16;
    return __builtin_bit_cast(float, x);
}
// async global->LDS, 16B per lane. LDS dest must be wave-uniform base + lane*16.
__device__ __forceinline__ void async16(ushort* lds, const ushort* g) {
    __builtin_amdgcn_global_load_lds(
        (const __attribute__((address_space(1))) unsigned int*)g,
        (__attribute__((address_space(3))) unsigned int*)lds, 16, 0, 0);
}

// ---------------------------------------------------------------------------
// Kernel 1: X fp32 -> bf16 (16.8M elems, 8 per thread)
// ---------------------------------------------------------------------------
__global__ __launch_bounds__(256) void convert_x(
    const float* __restrict__ X, ushort* __restrict__ Xb)
{
    size_t i = ((size_t)blockIdx.x * 256 + threadIdx.x) * 8;
    float4 a = *(const float4*)&X[i];
    float4 b = *(const float4*)&X[i + 4];
    bf16x8 o;
    o[0] = (short)f2bf(a.x); o[1] = (short)f2bf(a.y);
    o[2] = (short)f2bf(a.z); o[3] = (short)f2bf(a.w);
    o[4] = (short)f2bf(b.x); o[5] = (short)f2bf(b.y);
    o[6] = (short)f2bf(b.z); o[7] = (short)f2bf(b.w);
    *(bf16x8*)&Xb[i] = o;
}

// ---------------------------------------------------------------------------
// Kernel 2: W fp32 -> bf16, stacked [384][1024]. Wq scaled by log2e/sqrt(128).
// ---------------------------------------------------------------------------
__global__ __launch_bounds__(256) void convert_w(
    const float* __restrict__ Wq, const float* __restrict__ Wk,
    const float* __restrict__ Wv, ushort* __restrict__ Wb)
{
    int g = blockIdx.x * 256 + threadIdx.x;    // 0..49151
    size_t base = (size_t)g * 8;
    int sel = (int)(base >> 17);               // 128*1024 floats per W
    const float* W = sel == 0 ? Wq : (sel == 1 ? Wk : Wv);
    float s = (sel == 0) ? 0.12751744f : 1.0f; // log2(e)/sqrt(128) folded into Wq
    size_t off = base - (size_t)sel * 131072;
    float4 a = *(const float4*)&W[off];
    float4 b = *(const float4*)&W[off + 4];
    bf16x8 o;
    o[0] = (short)f2bf(a.x * s); o[1] = (short)f2bf(a.y * s);
    o[2] = (short)f2bf(a.z * s); o[3] = (short)f2bf(a.w * s);
    o[4] = (short)f2bf(b.x * s); o[5] = (short)f2bf(b.y * s);
    o[6] = (short)f2bf(b.z * s); o[7] = (short)f2bf(b.w * s);
    *(bf16x8*)&Wb[base] = o;
}

// ---------------------------------------------------------------------------
// Kernel 3: QKV GEMM, bf16, m97-style. BM=128, BN=64, BK=64, global_load_lds.
// out[m][n] = sum_k Xb[m][k] * Wb[n][k]
// ---------------------------------------------------------------------------
__global__ __launch_bounds__(256) void qkv_gemm(
    const ushort* __restrict__ Xb, const ushort* __restrict__ Wb,
    ushort* __restrict__ Qo, ushort* __restrict__ Ko, ushort* __restrict__ Vo)
{
    __shared__ ushort Al[128 * 64];   // 16KB, unpadded (global_load_lds)
    __shared__ ushort Bl[64 * 64];    // 8KB
    const int m0 = blockIdx.x * 128;
    const int n0 = blockIdx.y * 64;
    const int tid = threadIdx.x, lane = tid & 63, wave = tid >> 6;
    const int quad = lane >> 4, colL = lane & 15;
    const int wm = (wave & 1) * 64, wn = (wave >> 1) * 32;
    const int lr = lane >> 3, lc = (lane & 7) * 8;

    floatx4 acc[4][2] = {};

    for (int k0 = 0; k0 < C; k0 += 64) {
        for (int t = 0; t < 4; ++t) {
            int q = wave * 4 + t;             // 16 chunks of 1KB
            async16(&Al[q * 512 + lane * 8],
                    &Xb[(size_t)(m0 + q * 8 + lr) * C + k0 + lc]);
        }
        for (int t = 0; t < 2; ++t) {
            int q = wave * 2 + t;             // 8 chunks
            async16(&Bl[q * 512 + lane * 8],
                    &Wb[(size_t)(n0 + q * 8 + lr) * C + k0 + lc]);
        }
        __syncthreads();                      // drains vmcnt -> LDS ready

        bf16x8 af[2][4], bfr[2][2];
        for (int kk = 0; kk < 2; ++kk) {
            for (int mt = 0; mt < 4; ++mt)
                af[kk][mt] = *(const bf16x8*)&Al[(wm + mt * 16 + colL) * 64 + kk * 32 + quad * 8];
            for (int nt = 0; nt < 2; ++nt)
                bfr[kk][nt] = *(const bf16x8*)&Bl[(wn + nt * 16 + colL) * 64 + kk * 32 + quad * 8];
        }
        for (int kk = 0; kk < 2; ++kk)
            for (int mt = 0; mt < 4; ++mt)
                for (int nt = 0; nt < 2; ++nt)
                    acc[mt][nt] = __builtin_amdgcn_mfma_f32_16x16x32_bf16(
                        af[kk][mt], bfr[kk][nt], acc[mt][nt], 0, 0, 0);
        __syncthreads();
    }

    const int sel = n0 >> 7;                  // 0,0,1,1,2,2 over blockIdx.y
    ushort* dst = sel == 0 ? Qo : (sel == 1 ? Ko : Vo);
    const int h0 = n0 & 127;
    for (int mt = 0; mt < 4; ++mt)
        for (int nt = 0; nt < 2; ++nt)
            for (int r = 0; r < 4; ++r) {
                int row = m0 + wm + mt * 16 + quad * 4 + r;
                int h = h0 + wn + nt * 16 + colL;
                dst[(size_t)row * Hd + h] = f2bf(acc[mt][nt][r]);
            }
}

// ---------------------------------------------------------------------------
// Kernel 4: V [b][t][h] -> Vt [b][h][t]  (bf16), 64x64 tiles through LDS
// ---------------------------------------------------------------------------
__global__ __launch_bounds__(256) void transpose_v(
    const ushort* __restrict__ V, ushort* __restrict__ Vt)
{
    __shared__ ushort tl[64][68];
    const int t0 = blockIdx.x * 64;
    const int h0 = blockIdx.y * 64;
    const int b  = blockIdx.z;
    const int tid = threadIdx.x;

    for (int it = 0; it < 4; ++it) {
        int idx = tid + it * 256;
        int r  = idx >> 4;
        int c4 = idx & 15;
        ushort4 v = *(const ushort4*)&V[(size_t)(b * T + t0 + r) * Hd + h0 + c4 * 4];
        *(ushort4*)&tl[r][c4 * 4] = v;
    }
    __syncthreads();
    for (int it = 0; it < 4; ++it) {
        int idx = tid + it * 256;
        int rh = idx >> 4;
        int c4 = idx & 15;
        ushort4 o;
        o.x = tl[c4 * 4 + 0][rh];
        o.y = tl[c4 * 4 + 1][rh];
        o.z = tl[c4 * 4 + 2][rh];
        o.w = tl[c4 * 4 + 3][rh];
        *(ushort4*)&Vt[(size_t)(b * Hd + h0 + rh) * T + t0 + c4 * 4] = o;
    }
}

// ---------------------------------------------------------------------------
// Kernel 5: split-K causal flash attention partials.
// Block = (chunk c of 256 keys, qtile j of 64 rows, batch b); 4 waves,
// wave w owns q rows [64j+16w, +16). Valid iff c <= j>>2. Emits unnormalized
// O (bf16) + m,l (fp32, exp2-domain) per slot.
// LDS: Kl 16KB + Vl 16KB = 32KB; P scratch aliases Kl (extra barrier after QK).
// ---------------------------------------------------------------------------
__global__ __launch_bounds__(256, 4) void attn_partial(
    const ushort* __restrict__ Q, const ushort* __restrict__ Kg,
    const ushort* __restrict__ Vt, ushort* __restrict__ Opart,
    float* __restrict__ mpart, float* __restrict__ lpart)
{
    __shared__ ushort Kl[64 * 128];   // [key][h]
    __shared__ ushort Vl[128 * 64];   // [h][key]

    const int c = blockIdx.x, j = blockIdx.y, b = blockIdx.z;
    const int a_ = j >> 2;
    const int nch = a_ + 1;           // chunks needed for this qtile
    if (c >= nch) return;
    const int q0 = j * 64;
    const int kstart = c * 256;
    const bool lastc = (c == nch - 1);
    const int len = lastc ? (q0 + 64 - kstart) : 256;   // multiple of 64
    const int niter = len >> 6;

    const int tid = threadIdx.x, lane = tid & 63, wave = tid >> 6;
    const int quad = lane >> 4, colL = lane & 15;

    bf16x8 qa[4];
    {
        const ushort* qp = &Q[(size_t)(b * T + q0 + wave * 16 + colL) * Hd];
        for (int ks = 0; ks < 4; ++ks)
            qa[ks] = *(const bf16x8*)&qp[ks * 32 + quad * 8];
    }

    float m_r[4], l_r[4];
    for (int r = 0; r < 4; ++r) { m_r[r] = -__builtin_inff(); l_r[r] = 0.f; }
    floatx4 Oacc[8] = {};
    ushort* Pw = &Kl[wave * 1152];    // per-wave [16][72] P scratch inside Kl

    for (int it = 0; it < niter; ++it) {
        const int k0 = kstart + it * 64;
        const ushort* Kt = &Kg[((size_t)b * T + k0) * Hd];   // 16KB contiguous
        for (int t = 0; t < 4; ++t) {
            int q = wave * 4 + t;
            async16(&Kl[q * 512 + lane * 8], &Kt[q * 512 + lane * 8]);
        }
        for (int t = 0; t < 4; ++t) {
            int q = wave * 4 + t;
            int hrow = q * 8 + (lane >> 3);
            async16(&Vl[q * 512 + lane * 8],
                    &Vt[((size_t)b * Hd + hrow) * T + k0 + (lane & 7) * 8]);
        }
        __syncthreads();

        // S = Q K^T
        floatx4 accS[4] = {};
        for (int ks = 0; ks < 4; ++ks)
            for (int nt = 0; nt < 4; ++nt) {
                bf16x8 kb = *(const bf16x8*)&Kl[(nt * 16 + colL) * 128 + ks * 32 + quad * 8];
                accS[nt] = __builtin_amdgcn_mfma_f32_16x16x32_bf16(
                    qa[ks], kb, accS[nt], 0, 0, 0);
            }

        if (lastc && it == niter - 1) {
            for (int nt = 0; nt < 4; ++nt)
                for (int r = 0; r < 4; ++r) {
                    int colg = k0 + nt * 16 + colL;
                    int rowg = q0 + wave * 16 + quad * 4 + r;
                    if (colg > rowg) accS[nt][r] = -__builtin_inff();
                }
        }
        __syncthreads();   // everyone done reading Kl; P may alias it now

        float mnew[4], alpha[4], rsum[4];
        for (int r = 0; r < 4; ++r) {
            float mx = fmaxf(fmaxf(accS[0][r], accS[1][r]),
                             fmaxf(accS[2][r], accS[3][r]));
            for (int off = 1; off < 16; off <<= 1)
                mx = fmaxf(mx, __shfl_xor(mx, off, 64));
            mnew[r] = fmaxf(m_r[r], mx);
            alpha[r] = __builtin_amdgcn_exp2f(m_r[r] - mnew[r]);
            rsum[r] = 0.f;
        }
        for (int nt = 0; nt < 4; ++nt)
            for (int r = 0; r < 4; ++r) {
                float p = __builtin_amdgcn_exp2f(accS[nt][r] - mnew[r]);
                rsum[r] += p;
                Pw[(quad * 4 + r) * 72 + nt * 16 + colL] = f2bf(p);
            }
        for (int r = 0; r < 4; ++r) {
            float s = rsum[r];
            for (int off = 1; off < 16; off <<= 1)
                s += __shfl_xor(s, off, 64);
            l_r[r] = l_r[r] * alpha[r] + s;
            m_r[r] = mnew[r];
        }
        for (int th = 0; th < 8; ++th)
            for (int r = 0; r < 4; ++r) Oacc[th][r] *= alpha[r];

        // P (C-layout) -> A-layout via LDS; O += P V
        bf16x8 pa[2];
        for (int k2 = 0; k2 < 2; ++k2)
            pa[k2] = *(const bf16x8*)&Pw[colL * 72 + k2 * 32 + quad * 8];
        for (int th = 0; th < 8; ++th)
            for (int k2 = 0; k2 < 2; ++k2) {
                bf16x8 vb = *(const bf16x8*)&Vl[(th * 16 + colL) * 64 + k2 * 32 + quad * 8];
                Oacc[th] = __builtin_amdgcn_mfma_f32_16x16x32_bf16(
                    pa[k2], vb, Oacc[th], 0, 0, 0);
            }
        __syncthreads();   // P reads + Vl reads done before next staging
    }

    // compact slot index: pre(j) = j + 2a(a-1) + (j&3)*a,  a = j>>2
    const int slot = b * 144 + j + 2 * a_ * (a_ - 1) + (j & 3) * a_ + c;
    ushort* Op = &Opart[(size_t)slot * 8192];
    for (int th = 0; th < 8; ++th)
        for (int r = 0; r < 4; ++r)
            Op[(wave * 16 + quad * 4 + r) * 128 + th * 16 + colL] = f2bf(Oacc[th][r]);
    if (colL == 0)
        for (int r = 0; r < 4; ++r) {
            int row = wave * 16 + quad * 4 + r;
            mpart[(size_t)slot * 64 + row] = m_r[r];
            lpart[(size_t)slot * 64 + row] = l_r[r];
        }
}

// ---------------------------------------------------------------------------
// Kernel 6: merge partials (log-sum-exp in exp2 domain), write fp32 out.
// Block = (qtile j, batch b), 256 threads; thread owns (row = t>>2, 32 cols).
// ---------------------------------------------------------------------------
__global__ __launch_bounds__(256) void attn_combine(
    const ushort* __restrict__ Opart, const float* __restrict__ mpart,
    const float* __restrict__ lpart, float* __restrict__ out)
{
    const int j = blockIdx.x, b = blockIdx.y;
    const int a_ = j >> 2;
    const int nch = a_ + 1;
    const int base = b * 144 + j + 2 * a_ * (a_ - 1) + (j & 3) * a_;
    const int t = threadIdx.x;
    const int row = t >> 2;
    const int c0 = (t & 3) * 32;

    float M = -__builtin_inff();
    for (int c = 0; c < nch; ++c)
        M = fmaxf(M, mpart[(size_t)(base + c) * 64 + row]);
    float ltot = 0.f;
    for (int c = 0; c < nch; ++c)
        ltot += lpart[(size_t)(base + c) * 64 + row] *
                __builtin_amdgcn_exp2f(mpart[(size_t)(base + c) * 64 + row] - M);

    float o[32];
    for (int i = 0; i < 32; ++i) o[i] = 0.f;
    for (int c = 0; c < nch; ++c) {
        float wgt = __builtin_amdgcn_exp2f(mpart[(size_t)(base + c) * 64 + row] - M);
        const ushort* Op = &Opart[(size_t)(base + c) * 8192 + row * 128 + c0];
        for (int x = 0; x < 32; x += 8) {
            bf16x8 v = *(const bf16x8*)&Op[x];
            for (int i2 = 0; i2 < 8; ++i2)
                o[x + i2] += bf2f((ushort)v[i2]) * wgt;
        }
    }
    float inv = 1.0f / ltot;
    float* dst = &out[((size_t)(b * T) + j * 64 + row) * Hd + c0];
    for (int i = 0; i < 32; ++i) dst[i] = o[i] * inv;
}

// ---------------------------------------------------------------------------
extern "C" void kernel_launch(void* const* d_in, const int* in_sizes, int n_in,
                              void* d_out, int out_size, void* d_ws, size_t ws_size,
                              hipStream_t stream) {
    const float* x  = (const float*)d_in[0];
    const float* Wq = (const float*)d_in[1];
    const float* Wk = (const float*)d_in[2];
    const float* Wv = (const float*)d_in[3];
    float* out = (float*)d_out;

    // workspace layout (~70.6 MB total)
    char* w = (char*)d_ws;
    ushort* Xb  = (ushort*)w;  w += (size_t)NB * T * C * 2;        // 33.55 MB
    ushort* Wb  = (ushort*)w;  w += (size_t)384 * C * 2;           // 0.79 MB
    ushort* Qb  = (ushort*)w;  w += (size_t)NB * T * Hd * 2;       // 4.19 MB
    ushort* Kb  = (ushort*)w;  w += (size_t)NB * T * Hd * 2;
    ushort* Vb  = (ushort*)w;  w += (size_t)NB * T * Hd * 2;
    ushort* Vtb = (ushort*)w;  w += (size_t)NB * T * Hd * 2;
    ushort* Opart = (ushort*)w; w += (size_t)1152 * 8192 * 2;      // 18.87 MB
    float* mpart = (float*)w;  w += (size_t)1152 * 64 * 4;
    float* lpart = (float*)w;  w += (size_t)1152 * 64 * 4;

    convert_x<<<8192, 256, 0, stream>>>(x, Xb);
    convert_w<<<192, 256, 0, stream>>>(Wq, Wk, Wv, Wb);
    qkv_gemm<<<dim3(128, 6), 256, 0, stream>>>(Xb, Wb, Qb, Kb, Vb);
    transpose_v<<<dim3(T / 64, Hd / 64, NB), 256, 0, stream>>>(Vb, Vtb);
    attn_partial<<<dim3(8, 32, 8), 256, 0, stream>>>(Qb, Kb, Vtb, Opart, mpart, lpart);
    attn_combine<<<dim3(32, 8), 256, 0, stream>>>(Opart, mpart, lpart, out);
}

// Round 3
// 188.787 us; speedup vs baseline: 1.3072x; 1.1083x over previous
//
#include <hip/hip_runtime.h>
#include <hip/hip_bf16.h>

constexpr int NB = 8;      // batch
constexpr int T  = 2048;   // seq
constexpr int C  = 1024;   // embed
constexpr int Hd = 128;    // head size

typedef short bf16x8 __attribute__((ext_vector_type(8)));
typedef float floatx4 __attribute__((ext_vector_type(4)));

__device__ __forceinline__ ushort f2bf(float x) {
    return __builtin_bit_cast(ushort, __float2bfloat16(x));
}
__device__ __forceinline__ float bf2f(ushort u) {
    unsigned int x = ((unsigned int)u) << 16;
    return __builtin_bit_cast(float, x);
}
// async global->LDS, 16B per lane. LDS dest is wave-uniform base + lane*16.
__device__ __forceinline__ void async16(ushort* lds, const ushort* g) {
    __builtin_amdgcn_global_load_lds(
        (const __attribute__((address_space(1))) unsigned int*)g,
        (__attribute__((address_space(3))) unsigned int*)lds, 16, 0, 0);
}

// ---------------------------------------------------------------------------
// Kernel 1: X fp32 -> bf16
// ---------------------------------------------------------------------------
__global__ __launch_bounds__(256) void convert_x(
    const float* __restrict__ X, ushort* __restrict__ Xb)
{
    size_t i = ((size_t)blockIdx.x * 256 + threadIdx.x) * 8;
    float4 a = *(const float4*)&X[i];
    float4 b = *(const float4*)&X[i + 4];
    bf16x8 o;
    o[0] = (short)f2bf(a.x); o[1] = (short)f2bf(a.y);
    o[2] = (short)f2bf(a.z); o[3] = (short)f2bf(a.w);
    o[4] = (short)f2bf(b.x); o[5] = (short)f2bf(b.y);
    o[6] = (short)f2bf(b.z); o[7] = (short)f2bf(b.w);
    *(bf16x8*)&Xb[i] = o;
}

// ---------------------------------------------------------------------------
// Kernel 2: W fp32 -> bf16 stacked [384][1024]; Wq scaled by log2e/sqrt(128)
// ---------------------------------------------------------------------------
__global__ __launch_bounds__(256) void convert_w(
    const float* __restrict__ Wq, const float* __restrict__ Wk,
    const float* __restrict__ Wv, ushort* __restrict__ Wb)
{
    int g = blockIdx.x * 256 + threadIdx.x;
    size_t base = (size_t)g * 8;
    int sel = (int)(base >> 17);
    const float* W = sel == 0 ? Wq : (sel == 1 ? Wk : Wv);
    float s = (sel == 0) ? 0.12751744f : 1.0f;
    size_t off = base - (size_t)sel * 131072;
    float4 a = *(const float4*)&W[off];
    float4 b = *(const float4*)&W[off + 4];
    bf16x8 o;
    o[0] = (short)f2bf(a.x * s); o[1] = (short)f2bf(a.y * s);
    o[2] = (short)f2bf(a.z * s); o[3] = (short)f2bf(a.w * s);
    o[4] = (short)f2bf(b.x * s); o[5] = (short)f2bf(b.y * s);
    o[6] = (short)f2bf(b.z * s); o[7] = (short)f2bf(b.w * s);
    *(bf16x8*)&Wb[base] = o;
}

// ---------------------------------------------------------------------------
// Kernel 3: QKV GEMM bf16, BM=128 BN=64 BK=64, global_load_lds + XOR swizzle.
// LDS tiles store 16B chunk at physical index (chunk ^ (row&7)) within a row.
// ---------------------------------------------------------------------------
__global__ __launch_bounds__(256) void qkv_gemm(
    const ushort* __restrict__ Xb, const ushort* __restrict__ Wb,
    ushort* __restrict__ Qo, ushort* __restrict__ Ko, ushort* __restrict__ Vo)
{
    __shared__ ushort Al[128 * 64];   // 16KB
    __shared__ ushort Bl[64 * 64];    // 8KB
    const int m0 = blockIdx.x * 128;
    const int n0 = blockIdx.y * 64;
    const int tid = threadIdx.x, lane = tid & 63, wave = tid >> 6;
    const int quad = lane >> 4, colL = lane & 15;
    const int wm = (wave & 1) * 64, wn = (wave >> 1) * 32;
    const int lr = lane >> 3;                       // 0..7 row-within-chunkgroup
    const int lcs = ((lane & 7) ^ (lr & 7)) * 8;    // swizzled source column

    floatx4 acc[4][2] = {};

    for (int k0 = 0; k0 < C; k0 += 64) {
        for (int t = 0; t < 4; ++t) {
            int q = wave * 4 + t;                   // 0..15
            async16(&Al[q * 512 + lane * 8],
                    &Xb[(size_t)(m0 + q * 8 + lr) * C + k0 + lcs]);
        }
        for (int t = 0; t < 2; ++t) {
            int q = wave * 2 + t;                   // 0..7
            async16(&Bl[q * 512 + lane * 8],
                    &Wb[(size_t)(n0 + q * 8 + lr) * C + k0 + lcs]);
        }
        __syncthreads();

        bf16x8 af[2][4], bfr[2][2];
        for (int kk = 0; kk < 2; ++kk) {
            for (int mt = 0; mt < 4; ++mt)
                af[kk][mt] = *(const bf16x8*)
                    &Al[(wm + mt * 16 + colL) * 64 + (((kk * 4 + quad) ^ (colL & 7))) * 8];
            for (int nt = 0; nt < 2; ++nt)
                bfr[kk][nt] = *(const bf16x8*)
                    &Bl[(wn + nt * 16 + colL) * 64 + (((kk * 4 + quad) ^ (colL & 7))) * 8];
        }
        for (int kk = 0; kk < 2; ++kk)
            for (int mt = 0; mt < 4; ++mt)
                for (int nt = 0; nt < 2; ++nt)
                    acc[mt][nt] = __builtin_amdgcn_mfma_f32_16x16x32_bf16(
                        af[kk][mt], bfr[kk][nt], acc[mt][nt], 0, 0, 0);
        __syncthreads();
    }

    const int sel = n0 >> 7;
    ushort* dst = sel == 0 ? Qo : (sel == 1 ? Ko : Vo);
    const int h0 = n0 & 127;
    for (int mt = 0; mt < 4; ++mt)
        for (int nt = 0; nt < 2; ++nt)
            for (int r = 0; r < 4; ++r) {
                int row = m0 + wm + mt * 16 + quad * 4 + r;
                int h = h0 + wn + nt * 16 + colL;
                dst[(size_t)row * Hd + h] = f2bf(acc[mt][nt][r]);
            }
}

// ---------------------------------------------------------------------------
// Kernel 4: V [b][t][h] -> Vt [b][h][t]
// ---------------------------------------------------------------------------
__global__ __launch_bounds__(256) void transpose_v(
    const ushort* __restrict__ V, ushort* __restrict__ Vt)
{
    __shared__ ushort tl[64][68];
    const int t0 = blockIdx.x * 64;
    const int h0 = blockIdx.y * 64;
    const int b  = blockIdx.z;
    const int tid = threadIdx.x;

    for (int it = 0; it < 4; ++it) {
        int idx = tid + it * 256;
        int r  = idx >> 4;
        int c4 = idx & 15;
        ushort4 v = *(const ushort4*)&V[(size_t)(b * T + t0 + r) * Hd + h0 + c4 * 4];
        *(ushort4*)&tl[r][c4 * 4] = v;
    }
    __syncthreads();
    for (int it = 0; it < 4; ++it) {
        int idx = tid + it * 256;
        int rh = idx >> 4;
        int c4 = idx & 15;
        ushort4 o;
        o.x = tl[c4 * 4 + 0][rh];
        o.y = tl[c4 * 4 + 1][rh];
        o.z = tl[c4 * 4 + 2][rh];
        o.w = tl[c4 * 4 + 3][rh];
        *(ushort4*)&Vt[(size_t)(b * Hd + h0 + rh) * T + t0 + c4 * 4] = o;
    }
}

// ---------------------------------------------------------------------------
// Kernel 5: split-K causal flash attention partials.
// Block = (chunk c of 128 keys, qtile j of 64 rows, batch b); valid iff
// c < (j+2)>>1. Slot index: pre(j) = (u + (j&1))*(u+1), u=j>>1.
// LDS swizzled (chunk ^ row) for Kl (16 chunks/row) and Vl (8 chunks/row).
// ---------------------------------------------------------------------------
__global__ __launch_bounds__(256, 4) void attn_partial(
    const ushort* __restrict__ Q, const ushort* __restrict__ Kg,
    const ushort* __restrict__ Vt, ushort* __restrict__ Opart,
    float* __restrict__ mpart, float* __restrict__ lpart)
{
    __shared__ ushort Kl[64 * 128];   // [key][h] swizzled, 16KB
    __shared__ ushort Vl[128 * 64];   // [h][key] swizzled, 16KB

    const int c = blockIdx.x, j = blockIdx.y, b = blockIdx.z;
    const int nch = (j + 2) >> 1;
    if (c >= nch) return;
    const int q0 = j * 64;
    const int kstart = c * 128;
    const bool lastc = (c == nch - 1);
    const int len = lastc ? (q0 + 64 - kstart) : 128;
    const int niter = len >> 6;       // 1 or 2

    const int tid = threadIdx.x, lane = tid & 63, wave = tid >> 6;
    const int quad = lane >> 4, colL = lane & 15;

    bf16x8 qa[4];
    {
        const ushort* qp = &Q[(size_t)(b * T + q0 + wave * 16 + colL) * Hd];
        for (int ks = 0; ks < 4; ++ks)
            qa[ks] = *(const bf16x8*)&qp[ks * 32 + quad * 8];
    }

    float m_r[4], l_r[4];
    for (int r = 0; r < 4; ++r) { m_r[r] = -__builtin_inff(); l_r[r] = 0.f; }
    floatx4 Oacc[8] = {};
    ushort* Pw = &Kl[wave * 1152];    // per-wave [16][72] P scratch aliasing Kl

    for (int it = 0; it < niter; ++it) {
        const int k0 = kstart + it * 64;
        const ushort* Kt = &Kg[((size_t)b * T + k0) * Hd];
        for (int t = 0; t < 4; ++t) {
            int q = wave * 4 + t;                       // 0..15
            int rp = q * 4 + (lane >> 4);               // key row 0..63
            async16(&Kl[q * 512 + lane * 8],
                    &Kt[rp * 128 + ((lane & 15) ^ (rp & 15)) * 8]);
        }
        for (int t = 0; t < 4; ++t) {
            int q = wave * 4 + t;                       // 0..15
            int hp = q * 8 + (lane >> 3);               // h row 0..127
            async16(&Vl[q * 512 + lane * 8],
                    &Vt[((size_t)b * Hd + hp) * T + k0 +
                        (((lane & 7) ^ ((lane >> 3) & 7))) * 8]);
        }
        __syncthreads();

        // S = Q K^T (swizzled Kl reads: 2-way banks, free)
        floatx4 accS[4] = {};
        for (int ks = 0; ks < 4; ++ks)
            for (int nt = 0; nt < 4; ++nt) {
                bf16x8 kb = *(const bf16x8*)
                    &Kl[(nt * 16 + colL) * 128 + (((ks * 4 + quad) ^ colL)) * 8];
                accS[nt] = __builtin_amdgcn_mfma_f32_16x16x32_bf16(
                    qa[ks], kb, accS[nt], 0, 0, 0);
            }

        if (lastc && it == niter - 1) {
            for (int nt = 0; nt < 4; ++nt)
                for (int r = 0; r < 4; ++r) {
                    int colg = k0 + nt * 16 + colL;
                    int rowg = q0 + wave * 16 + quad * 4 + r;
                    if (colg > rowg) accS[nt][r] = -__builtin_inff();
                }
        }
        __syncthreads();   // Kl reads done; P may alias it

        float mnew[4], alpha[4], rsum[4];
        for (int r = 0; r < 4; ++r) {
            float mx = fmaxf(fmaxf(accS[0][r], accS[1][r]),
                             fmaxf(accS[2][r], accS[3][r]));
            for (int off = 1; off < 16; off <<= 1)
                mx = fmaxf(mx, __shfl_xor(mx, off, 64));
            mnew[r] = fmaxf(m_r[r], mx);
            alpha[r] = __builtin_amdgcn_exp2f(m_r[r] - mnew[r]);
            rsum[r] = 0.f;
        }
        for (int nt = 0; nt < 4; ++nt)
            for (int r = 0; r < 4; ++r) {
                float p = __builtin_amdgcn_exp2f(accS[nt][r] - mnew[r]);
                rsum[r] += p;
                Pw[(quad * 4 + r) * 72 + nt * 16 + colL] = f2bf(p);
            }
        for (int r = 0; r < 4; ++r) {
            float s = rsum[r];
            for (int off = 1; off < 16; off <<= 1)
                s += __shfl_xor(s, off, 64);
            l_r[r] = l_r[r] * alpha[r] + s;
            m_r[r] = mnew[r];
        }
        for (int th = 0; th < 8; ++th)
            for (int r = 0; r < 4; ++r) Oacc[th][r] *= alpha[r];

        // P (C-layout) -> A-layout via LDS; O += P V
        bf16x8 pa[2];
        for (int k2 = 0; k2 < 2; ++k2)
            pa[k2] = *(const bf16x8*)&Pw[colL * 72 + k2 * 32 + quad * 8];
        for (int th = 0; th < 8; ++th)
            for (int k2 = 0; k2 < 2; ++k2) {
                bf16x8 vb = *(const bf16x8*)
                    &Vl[(th * 16 + colL) * 64 + (((k2 * 4 + quad) ^ (colL & 7))) * 8];
                Oacc[th] = __builtin_amdgcn_mfma_f32_16x16x32_bf16(
                    pa[k2], vb, Oacc[th], 0, 0, 0);
            }
        __syncthreads();
    }

    const int u = j >> 1;
    const int slot = b * 272 + (u + (j & 1)) * (u + 1) + c;
    ushort* Op = &Opart[(size_t)slot * 8192];
    for (int th = 0; th < 8; ++th)
        for (int r = 0; r < 4; ++r)
            Op[(wave * 16 + quad * 4 + r) * 128 + th * 16 + colL] = f2bf(Oacc[th][r]);
    if (colL == 0)
        for (int r = 0; r < 4; ++r) {
            int row = wave * 16 + quad * 4 + r;
            mpart[(size_t)slot * 64 + row] = m_r[r];
            lpart[(size_t)slot * 64 + row] = l_r[r];
        }
}

// ---------------------------------------------------------------------------
// Kernel 6: merge partials, write fp32 out.
// ---------------------------------------------------------------------------
__global__ __launch_bounds__(256) void attn_combine(
    const ushort* __restrict__ Opart, const float* __restrict__ mpart,
    const float* __restrict__ lpart, float* __restrict__ out)
{
    const int j = blockIdx.x, b = blockIdx.y;
    const int nch = (j + 2) >> 1;
    const int u = j >> 1;
    const int base = b * 272 + (u + (j & 1)) * (u + 1);
    const int t = threadIdx.x;
    const int row = t >> 2;
    const int c0 = (t & 3) * 32;

    float M = -__builtin_inff();
    for (int c = 0; c < nch; ++c)
        M = fmaxf(M, mpart[(size_t)(base + c) * 64 + row]);
    float ltot = 0.f;
    for (int c = 0; c < nch; ++c)
        ltot += lpart[(size_t)(base + c) * 64 + row] *
                __builtin_amdgcn_exp2f(mpart[(size_t)(base + c) * 64 + row] - M);

    float o[32];
    for (int i = 0; i < 32; ++i) o[i] = 0.f;
    for (int c = 0; c < nch; ++c) {
        float wgt = __builtin_amdgcn_exp2f(mpart[(size_t)(base + c) * 64 + row] - M);
        const ushort* Op = &Opart[(size_t)(base + c) * 8192 + row * 128 + c0];
        for (int x = 0; x < 32; x += 8) {
            bf16x8 v = *(const bf16x8*)&Op[x];
            for (int i2 = 0; i2 < 8; ++i2)
                o[x + i2] += bf2f((ushort)v[i2]) * wgt;
        }
    }
    float inv = 1.0f / ltot;
    float* dst = &out[((size_t)(b * T) + j * 64 + row) * Hd + c0];
    for (int i = 0; i < 32; ++i) dst[i] = o[i] * inv;
}

// ---------------------------------------------------------------------------
extern "C" void kernel_launch(void* const* d_in, const int* in_sizes, int n_in,
                              void* d_out, int out_size, void* d_ws, size_t ws_size,
                              hipStream_t stream) {
    const float* x  = (const float*)d_in[0];
    const float* Wq = (const float*)d_in[1];
    const float* Wk = (const float*)d_in[2];
    const float* Wv = (const float*)d_in[3];
    float* out = (float*)d_out;

    // ws layout (~53.5 MB). Opart ALIASES Xb+Wb: Xb/Wb are dead once
    // qkv_gemm completes; attn_partial (which writes Opart) runs after it
    // on the same stream.
    char* w = (char*)d_ws;
    ushort* Opart = (ushort*)w;                            // 2176*8192*2 = 35.65 MB
    ushort* Xb = (ushort*)w;                               // 33.55 MB (aliased)
    ushort* Wb = (ushort*)(w + (size_t)NB * T * C * 2);    // 0.79 MB (aliased)
    w += (size_t)2176 * 8192 * 2;
    ushort* Qb  = (ushort*)w;  w += (size_t)NB * T * Hd * 2;
    ushort* Kb  = (ushort*)w;  w += (size_t)NB * T * Hd * 2;
    ushort* Vb  = (ushort*)w;  w += (size_t)NB * T * Hd * 2;
    ushort* Vtb = (ushort*)w;  w += (size_t)NB * T * Hd * 2;
    float* mpart = (float*)w;  w += (size_t)2176 * 64 * 4;
    float* lpart = (float*)w;  w += (size_t)2176 * 64 * 4;

    convert_x<<<8192, 256, 0, stream>>>(x, Xb);
    convert_w<<<192, 256, 0, stream>>>(Wq, Wk, Wv, Wb);
    qkv_gemm<<<dim3(128, 6), 256, 0, stream>>>(Xb, Wb, Qb, Kb, Vb);
    transpose_v<<<dim3(T / 64, Hd / 64, NB), 256, 0, stream>>>(Vb, Vtb);
    attn_partial<<<dim3(16, 32, 8), 256, 0, stream>>>(Qb, Kb, Vtb, Opart, mpart, lpart);
    attn_combine<<<dim3(32, 8), 256, 0, stream>>>(Opart, mpart, lpart, out);
}